// Round 3
// baseline (215.864 us; speedup 1.0000x reference)
//
#include <hip/hip_runtime.h>
#include <math.h>

// Problem constants: B=32 batches, N=64 points, D=64 hidden.
#define BB 32
#define NN 64
#define DD 64
constexpr int MAT = BB * NN * NN;           // one (B,N,N) matrix = 131072 floats
constexpr int DJ_OFF = 6 * MAT;             // dj-pack: [b][i][jp][8] floats
constexpr int DJ_PER_B = 64 * 32 * 8;       // 16384 floats per batch
constexpr int POOLED_OFF = DJ_OFF + BB * DJ_PER_B;

typedef float v2f __attribute__((ext_vector_type(2)));

// ---------------------------------------------------------------------------
// Phase 1 (grid B*7): blocks m=0..5 compute the six bilinear attention
// matrices (scaled by -0.125*log2e); m4 = E_jl stored as exp2, PAIR-
// INTERLEAVED over j: [jp][l][2]; m5 = R_kl stored as exp2. Block m=6 builds
// the per-(i, j-pair) displacement pack {x0,x1,y0,y1,z0,z1,0,0} used via
// s_load in the main kernel.
// Key identity: q_i.k_j = aug(p_i)^T (W_A aug W_B aug^T) aug(p_j), 4x4 form.
// ---------------------------------------------------------------------------
__global__ __launch_bounds__(256) void simplex_phase1(
    const float* __restrict__ pc,
    const float* __restrict__ Wq,  const float* __restrict__ bq,
    const float* __restrict__ Wk1, const float* __restrict__ bk1,
    const float* __restrict__ Wk2, const float* __restrict__ bk2,
    const float* __restrict__ Wk3, const float* __restrict__ bk3,
    float* __restrict__ ws)
{
  const int blk = blockIdx.x;
  const int m   = blk % 7;
  const int b   = blk / 7;
  const int tid = threadIdx.x;

  __shared__ float M[4][4];
  __shared__ float P[NN][3];

  if (m < 6 && tid < 16) {
    int r = tid >> 2, c = tid & 3;
    const float *WA = Wq, *bA = bq, *WB = Wk1, *bB = bk1;
    switch (m) {
      case 0: WA = Wq;  bA = bq;  WB = Wk1; bB = bk1; break; // A_ij  (q,  k1)
      case 1: WA = Wq;  bA = bq;  WB = Wk2; bB = bk2; break; // A_ik  (q,  k2)
      case 2: WA = Wq;  bA = bq;  WB = Wk3; bB = bk3; break; // A_il  (q,  k3)
      case 3: WA = Wk2; bA = bk2; WB = Wk1; bB = bk1; break; // A_jkT (r=k, c=j)
      case 4: WA = Wk1; bA = bk1; WB = Wk3; bB = bk3; break; // E_jl  (r=j, c=l)
      case 5: WA = Wk2; bA = bk2; WB = Wk3; bB = bk3; break; // R_kl  (r=k, c=l)
    }
    float s = 0.f;
    for (int d = 0; d < DD; ++d) {
      float va = (r < 3) ? WA[r * DD + d] : bA[d];
      float vb = (c < 3) ? WB[c * DD + d] : bB[d];
      s = fmaf(va, vb, s);
    }
    M[r][c] = s;
  }
  if (tid < NN * 3) {
    ((float*)P)[tid] = pc[b * NN * 3 + tid];
  }
  __syncthreads();

  if (m == 6) {
    // dj-pack: [i][jp][8] = {x(2j),x(2j+1), y.., y.., z.., z.., 0, 0}
    for (int idx = tid; idx < DJ_PER_B; idx += 256) {
      int word = idx & 7;
      int jp   = (idx >> 3) & 31;
      int i    = idx >> 8;
      float v = 0.f;
      if (word < 6) {
        int axis = word >> 1;
        int j    = jp * 2 + (word & 1);
        v = P[j][axis] - P[i][axis];
      }
      ws[DJ_OFF + b * DJ_PER_B + idx] = v;
    }
    return;
  }

  const float scale2 = -0.125f * 1.4426950408889634f; // -scale*log2(e)

  for (int it = 0; it < 16; ++it) {
    int g = tid + 256 * it;        // 0..4095
    int r = g >> 6, c = g & 63;
    float ar0 = P[r][0], ar1 = P[r][1], ar2 = P[r][2];
    float ac0 = P[c][0], ac1 = P[c][1], ac2 = P[c][2];
    float t0 = fmaf(M[0][0], ac0, fmaf(M[0][1], ac1, fmaf(M[0][2], ac2, M[0][3])));
    float t1 = fmaf(M[1][0], ac0, fmaf(M[1][1], ac1, fmaf(M[1][2], ac2, M[1][3])));
    float t2 = fmaf(M[2][0], ac0, fmaf(M[2][1], ac1, fmaf(M[2][2], ac2, M[2][3])));
    float t3 = fmaf(M[3][0], ac0, fmaf(M[3][1], ac1, fmaf(M[3][2], ac2, M[3][3])));
    float v = fmaf(ar0, t0, fmaf(ar1, t1, fmaf(ar2, t2, t3))) * scale2;
    if (m == 4) {
      // exp2, pair-interleaved over j (=r): [jp][l][2]
      float e = __builtin_amdgcn_exp2f(v);
      ws[4 * MAT + b * 4096 + ((r >> 1) << 7) + (c << 1) + (r & 1)] = e;
    } else if (m == 5) {
      ws[5 * MAT + b * 4096 + g] = __builtin_amdgcn_exp2f(v);
    } else {
      ws[m * MAT + b * 4096 + g] = v;
    }
  }
  if (m == 0 && tid == 0) ws[POOLED_OFF + b] = 0.f;  // zero pooled[b]
}

// ---------------------------------------------------------------------------
// Main kernel: one block per (b, anchor i). LANE = l; j runs as PAIRS in the
// inner loop; waves split k with a 4-k unroll (halves DS + SMEM traffic per
// cell vs the 2-k version and doubles the ILP window). T is laid out
// [jp][j01][t] so a lane's 4 T values are one ds_write_b128 and the inner
// loop reads them as 2x ds_read_b128 (uniform -> broadcast).
//   x = 1 + T_jk * E_jl * (R_kl * w_il)   ;  gate = 1/x
//   det = d_j . (d_k x d_l)               ;  acc += gate*det^2 (paired rcp)
// Per jp-iter (8 cells): 1 ds_read_b64 (E) + 2 ds_read_b128 (T) + 2 s_load.
// R1/R2 lesson: inline-asm packing REGRESSED (sched barriers + pair glue);
// body stays pure C for compiler scheduling.
// LDS = 16KB (sE) + 4KB (sT) = 20480 B exactly -> 8 blocks/CU.
// ---------------------------------------------------------------------------
__global__ __launch_bounds__(256, 8) void simplex_main(
    const float* __restrict__ pc,
    const float* __restrict__ ws_in,
    float* __restrict__ pooled)
{
  const int b    = blockIdx.x >> 6;
  const int i    = blockIdx.x & 63;
  const int tid  = threadIdx.x;
  const int lane = tid & 63;
  const int wu   = __builtin_amdgcn_readfirstlane(tid >> 6);

  __shared__ __align__(16) float sE[4096];   // E pair-interleaved [jp][l][2]
  __shared__ __align__(16) float sT[1024];   // per-wave T: [w][jp][j01][t0..3]

  const float* m0  = ws_in + 0 * MAT + (b * 64 + i) * 64; // A_ij[j]
  const float* m1  = ws_in + 1 * MAT + (b * 64 + i) * 64; // A_ik[k]
  const float* m2  = ws_in + 2 * MAT + (b * 64 + i) * 64; // A_il[l]
  const float* m3  = ws_in + 3 * MAT + b * 4096;          // A_jkT[k][j]
  const float* m5  = ws_in + 5 * MAT + b * 4096;          // R_kl[k][l]
  const float* m4  = ws_in + 4 * MAT + b * 4096;          // E interleaved
  const float* djp = ws_in + DJ_OFF + b * DJ_PER_B + i * 256; // [jp][8]
  const float* pcb = pc + b * 192;                        // batch points

  // ---- stage E (16 KB) ----
  {
    const float4* src = (const float4*)m4;
    float4* dst = (float4*)sE;
    dst[tid]       = src[tid];
    dst[tid + 256] = src[tid + 256];
    dst[tid + 512] = src[tid + 512];
    dst[tid + 768] = src[tid + 768];
  }
  // anchor point (uniform -> s_load) and per-lane point l
  const float pix = pcb[i * 3 + 0], piy = pcb[i * 3 + 1], piz = pcb[i * 3 + 2];
  const float dlx = pcb[lane * 3 + 0] - pix;
  const float dly = pcb[lane * 3 + 1] - piy;
  const float dlz = pcb[lane * 3 + 2] - piz;
  __syncthreads();

  const float wl  = __builtin_amdgcn_exp2f(m2[lane]); // exp2(A_il[l]) per-lane
  const float aij = m0[lane];                          // lane also plays j here
  float* sTw = sT + wu * 256;
  float acc = 0.f;

  for (int kk0 = 4 * wu; kk0 < 64; kk0 += 16) {
    const int kk = __builtin_amdgcn_readfirstlane(kk0);
    float cxA[4], cyA[4], czA[4], mmA[4], tqa[4];
#pragma unroll
    for (int t = 0; t < 4; ++t) {
      const int k = kk + t;
      // d_k from uniform s_loads of pc
      const float dkx = pcb[k * 3 + 0] - pix;
      const float dky = pcb[k * 3 + 1] - piy;
      const float dkz = pcb[k * 3 + 2] - piz;
      cxA[t] = dky * dlz - dkz * dly;              // d_k x d_l (per-lane)
      cyA[t] = dkz * dlx - dkx * dlz;
      czA[t] = dkx * dly - dky * dlx;
      mmA[t] = m5[k * 64 + lane] * wl;             // R_kl * w_il
      // T for this k (lane plays j): exp2(a_ij + a_jk + a_ik)
      tqa[t] = __builtin_amdgcn_exp2f(aij + m3[k * 64 + lane] + m1[k]);
    }
    // one b128 write: lane j's 4 T values -> sT[w][j>>1][j&1][0..3]
    {
      float4 tqv = {tqa[0], tqa[1], tqa[2], tqa[3]};
      *(float4*)&sTw[(lane >> 1) * 8 + (lane & 1) * 4] = tqv;
    }
    // same-wave LDS write->read: compiler inserts lgkmcnt wait; no barrier.
#pragma unroll 2
    for (int jp = 0; jp < 32; ++jp) {
      const float4 A  = *(const float4*)(djp + jp * 8);     // {x0,x1,y0,y1}
      const v2f    zz = *(const v2f*)(djp + jp * 8 + 4);    // {z0,z1}
      const v2f E01 = *(const v2f*)&sE[jp * 128 + lane * 2]; // per-lane b64
      const float4 Tq0 = *(const float4*)&sTw[jp * 8];       // j0, t=0..3
      const float4 Tq1 = *(const float4*)&sTw[jp * 8 + 4];   // j1, t=0..3
      const float T0[4] = {Tq0.x, Tq0.y, Tq0.z, Tq0.w};
      const float T1[4] = {Tq1.x, Tq1.y, Tq1.z, Tq1.w};
#pragma unroll
      for (int t = 0; t < 4; ++t) {
        const float e0 = E01.x * mmA[t];
        const float e1 = E01.y * mmA[t];
        const float x0 = fmaf(T0[t], e0, 1.f);
        const float x1 = fmaf(T1[t], e1, 1.f);
        const float det0 = fmaf(A.x, cxA[t], fmaf(A.z, cyA[t], zz.x * czA[t]));
        const float det1 = fmaf(A.y, cxA[t], fmaf(A.w, cyA[t], zz.y * czA[t]));
        const float den = x0 * x1;                // paired-rcp combine
        const float rd  = __builtin_amdgcn_rcpf(den);
        const float num = fmaf(det0 * det0, x1, det1 * det1 * x0);
        acc = fmaf(num, rd, acc);
      }
    }
  }

  // reduce: lanes sum over l; waves sum over their k slices.
  for (int s = 32; s; s >>= 1) acc += __shfl_xor(acc, s, 64);
  __syncthreads();                 // all waves done reading sT
  if (lane == 0) sT[wu] = acc;     // reuse sT as wsum
  __syncthreads();
  if (tid == 0) {
    float blocksum = sT[0] + sT[1] + sT[2] + sT[3];
    atomicAdd(&pooled[b], blocksum * (1.f / 16777216.f)); // / N^4
  }
}

// ---------------------------------------------------------------------------
// Final tiny MLP: out[b] = gelu_tanh(pooled[b]*W1 + b1) @ W2 + b2
// ---------------------------------------------------------------------------
__global__ void simplex_final(
    const float* __restrict__ pooled,
    const float* __restrict__ W1, const float* __restrict__ b1,
    const float* __restrict__ W2, const float* __restrict__ b2,
    float* __restrict__ out)
{
  int t = threadIdx.x;
  if (t < BB) {
    float x = pooled[t];
    float o = b2[0];
    for (int c = 0; c < 32; ++c) {
      float z  = fmaf(x, W1[c], b1[c]);
      float z3 = z * z * z;
      float y  = 0.7978845608028654f * fmaf(0.044715f, z3, z);
      float ay = fabsf(y);
      float e  = __builtin_amdgcn_exp2f(2.8853900817779268f * ay);
      float th = 1.f - 2.f / (e + 1.f);
      th = copysignf(th, y);
      float gl = 0.5f * z * (1.f + th);
      o = fmaf(gl, W2[c], o);
    }
    out[t] = o;
  }
}

// ---------------------------------------------------------------------------
extern "C" void kernel_launch(void* const* d_in, const int* in_sizes, int n_in,
                              void* d_out, int out_size, void* d_ws, size_t ws_size,
                              hipStream_t stream) {
  (void)in_sizes; (void)n_in; (void)out_size; (void)ws_size;
  const float* pc  = (const float*)d_in[0];
  const float* Wq  = (const float*)d_in[1];
  const float* bq  = (const float*)d_in[2];
  const float* Wk1 = (const float*)d_in[3];
  const float* bk1 = (const float*)d_in[4];
  const float* Wk2 = (const float*)d_in[5];
  const float* bk2 = (const float*)d_in[6];
  const float* Wk3 = (const float*)d_in[7];
  const float* bk3 = (const float*)d_in[8];
  const float* W1  = (const float*)d_in[9];
  const float* b1  = (const float*)d_in[10];
  const float* W2  = (const float*)d_in[11];
  const float* b2  = (const float*)d_in[12];

  float* ws     = (float*)d_ws;
  float* pooled = ws + POOLED_OFF;
  float* out    = (float*)d_out;

  hipLaunchKernelGGL(simplex_phase1, dim3(BB * 7), dim3(256), 0, stream,
                     pc, Wq, bq, Wk1, bk1, Wk2, bk2, Wk3, bk3, ws);
  hipLaunchKernelGGL(simplex_main, dim3(BB * NN), dim3(256), 0, stream,
                     pc, ws, pooled);
  hipLaunchKernelGGL(simplex_final, dim3(1), dim3(64), 0, stream,
                     pooled, W1, b1, W2, b2, out);
}

// Round 4
// 198.733 us; speedup vs baseline: 1.0862x; 1.0862x over previous
//
#include <hip/hip_runtime.h>
#include <math.h>

// Problem constants: B=32 batches, N=64 points, D=64 hidden.
#define BB 32
#define NN 64
#define DD 64
constexpr int MAT = BB * NN * NN;           // one (B,N,N) matrix = 131072 floats
constexpr int DJ_OFF = 6 * MAT;             // dj-pack: [b][i][jp][8] floats
constexpr int DJ_PER_B = 64 * 32 * 8;       // 16384 floats per batch
constexpr int POOLED_OFF = DJ_OFF + BB * DJ_PER_B;

typedef float v2f __attribute__((ext_vector_type(2)));

// Per-op packed-FP32 asm. R1 lesson: this regressed when operands were
// SMEM-resident (s->v mov glue). This time ALL operands are VGPR pairs
// (dj staged in LDS), so each asm is glue-free.
#define PKMUL(d, a, b_) \
  asm("v_pk_mul_f32 %0, %1, %2" : "=v"(d) : "v"(a), "v"(b_))
#define PKFMA(d, a, b_, c_) \
  asm("v_pk_fma_f32 %0, %1, %2, %3" : "=v"(d) : "v"(a), "v"(b_), "v"(c_))

// ---------------------------------------------------------------------------
// Phase 1 (grid B*7): blocks m=0..5 compute the six bilinear attention
// matrices (scaled by -0.125*log2e); m4 = E_jl stored as exp2, PAIR-
// INTERLEAVED over j: [jp][l][2]; m5 = R_kl stored as exp2. Block m=6 builds
// the per-(i, j-pair) displacement pack {x0,x1,y0,y1,z0,z1,0,0}.
// Key identity: q_i.k_j = aug(p_i)^T (W_A aug W_B aug^T) aug(p_j), 4x4 form.
// ---------------------------------------------------------------------------
__global__ __launch_bounds__(256) void simplex_phase1(
    const float* __restrict__ pc,
    const float* __restrict__ Wq,  const float* __restrict__ bq,
    const float* __restrict__ Wk1, const float* __restrict__ bk1,
    const float* __restrict__ Wk2, const float* __restrict__ bk2,
    const float* __restrict__ Wk3, const float* __restrict__ bk3,
    float* __restrict__ ws)
{
  const int blk = blockIdx.x;
  const int m   = blk % 7;
  const int b   = blk / 7;
  const int tid = threadIdx.x;

  __shared__ float M[4][4];
  __shared__ float P[NN][3];

  if (m < 6 && tid < 16) {
    int r = tid >> 2, c = tid & 3;
    const float *WA = Wq, *bA = bq, *WB = Wk1, *bB = bk1;
    switch (m) {
      case 0: WA = Wq;  bA = bq;  WB = Wk1; bB = bk1; break; // A_ij  (q,  k1)
      case 1: WA = Wq;  bA = bq;  WB = Wk2; bB = bk2; break; // A_ik  (q,  k2)
      case 2: WA = Wq;  bA = bq;  WB = Wk3; bB = bk3; break; // A_il  (q,  k3)
      case 3: WA = Wk2; bA = bk2; WB = Wk1; bB = bk1; break; // A_jkT (r=k, c=j)
      case 4: WA = Wk1; bA = bk1; WB = Wk3; bB = bk3; break; // E_jl  (r=j, c=l)
      case 5: WA = Wk2; bA = bk2; WB = Wk3; bB = bk3; break; // R_kl  (r=k, c=l)
    }
    float s = 0.f;
    for (int d = 0; d < DD; ++d) {
      float va = (r < 3) ? WA[r * DD + d] : bA[d];
      float vb = (c < 3) ? WB[c * DD + d] : bB[d];
      s = fmaf(va, vb, s);
    }
    M[r][c] = s;
  }
  if (tid < NN * 3) {
    ((float*)P)[tid] = pc[b * NN * 3 + tid];
  }
  __syncthreads();

  if (m == 6) {
    // dj-pack: [i][jp][8] = {x(2j),x(2j+1), y.., y.., z.., z.., 0, 0}
    for (int idx = tid; idx < DJ_PER_B; idx += 256) {
      int word = idx & 7;
      int jp   = (idx >> 3) & 31;
      int i    = idx >> 8;
      float v = 0.f;
      if (word < 6) {
        int axis = word >> 1;
        int j    = jp * 2 + (word & 1);
        v = P[j][axis] - P[i][axis];
      }
      ws[DJ_OFF + b * DJ_PER_B + idx] = v;
    }
    return;
  }

  const float scale2 = -0.125f * 1.4426950408889634f; // -scale*log2(e)

  for (int it = 0; it < 16; ++it) {
    int g = tid + 256 * it;        // 0..4095
    int r = g >> 6, c = g & 63;
    float ar0 = P[r][0], ar1 = P[r][1], ar2 = P[r][2];
    float ac0 = P[c][0], ac1 = P[c][1], ac2 = P[c][2];
    float t0 = fmaf(M[0][0], ac0, fmaf(M[0][1], ac1, fmaf(M[0][2], ac2, M[0][3])));
    float t1 = fmaf(M[1][0], ac0, fmaf(M[1][1], ac1, fmaf(M[1][2], ac2, M[1][3])));
    float t2 = fmaf(M[2][0], ac0, fmaf(M[2][1], ac1, fmaf(M[2][2], ac2, M[2][3])));
    float t3 = fmaf(M[3][0], ac0, fmaf(M[3][1], ac1, fmaf(M[3][2], ac2, M[3][3])));
    float v = fmaf(ar0, t0, fmaf(ar1, t1, fmaf(ar2, t2, t3))) * scale2;
    if (m == 4) {
      // exp2, pair-interleaved over j (=r): [jp][l][2]
      float e = __builtin_amdgcn_exp2f(v);
      ws[4 * MAT + b * 4096 + ((r >> 1) << 7) + (c << 1) + (r & 1)] = e;
    } else if (m == 5) {
      ws[5 * MAT + b * 4096 + g] = __builtin_amdgcn_exp2f(v);
    } else {
      ws[m * MAT + b * 4096 + g] = v;
    }
  }
  if (m == 0 && tid == 0) ws[POOLED_OFF + b] = 0.f;  // zero pooled[b]
}

// ---------------------------------------------------------------------------
// Main kernel: one block per (b, anchor i). LANE = l; j runs as PAIRS in the
// inner loop; waves split k (2-k unroll) — R0 structure (best measured).
// Changes vs R0: (1) dj-pack staged into LDS (sD) and read as broadcast
// ds_read_b128+b64 — removes s_load/ds_read lgkmcnt mixing AND makes the
// det operands VGPR-resident; (2) the 6 packable ops per t forced to
// v_pk_{mul,fma}_f32 via glue-free per-op asm (all operands VGPR pairs).
//   x = 1 + T_jk * E_jl * (R_kl * w_il)   ;  gate = 1/x
//   det = d_j . (d_k x d_l)               ;  acc += gate*det^2 (paired rcp)
// LDS = 16K (sE) + 1K (sD) + 2K (sT) + dXYZ + wsum = 20480 B -> 8 blocks/CU.
// ---------------------------------------------------------------------------
__global__ __launch_bounds__(256, 8) void simplex_main(
    const float* __restrict__ pc,
    const float* __restrict__ ws_in,
    float* __restrict__ pooled)
{
  const int b    = blockIdx.x >> 6;
  const int i    = blockIdx.x & 63;
  const int tid  = threadIdx.x;
  const int lane = tid & 63;
  const int wu   = __builtin_amdgcn_readfirstlane(tid >> 6);

  __shared__ __align__(16) float sE[4096];   // E pair-interleaved [jp][l][2]
  __shared__ __align__(16) float sD[256];    // dj-pack [jp][8]
  __shared__ float sT[512];                  // per-wave T rows: [w][2][64]
  __shared__ float dX[NN], dY[NN], dZ[NN];
  __shared__ float wsum[4];

  const float* m0  = ws_in + 0 * MAT + (b * 64 + i) * 64; // A_ij[j]
  const float* m1  = ws_in + 1 * MAT + (b * 64 + i) * 64; // A_ik[k]
  const float* m2  = ws_in + 2 * MAT + (b * 64 + i) * 64; // A_il[l]
  const float* m3  = ws_in + 3 * MAT + b * 4096;          // A_jkT[k][j]
  const float* m4  = ws_in + 4 * MAT + b * 4096;          // E interleaved
  const float* m5  = ws_in + 5 * MAT + b * 4096;          // R_kl[k][l]
  const float* djp = ws_in + DJ_OFF + b * DJ_PER_B + i * 256; // [jp][8]

  // ---- stage E (16 KB), dj-pack (1 KB), displacements ----
  {
    const float4* src = (const float4*)m4;
    float4* dst = (float4*)sE;
    dst[tid]       = src[tid];
    dst[tid + 256] = src[tid + 256];
    dst[tid + 512] = src[tid + 512];
    dst[tid + 768] = src[tid + 768];
  }
  if (tid < 64) {
    ((float4*)sD)[tid] = ((const float4*)djp)[tid];
  }
  if (tid >= 64 && tid < 128) {
    const int p = tid - 64;
    const float pix = pc[(b * 64 + i) * 3 + 0];
    const float piy = pc[(b * 64 + i) * 3 + 1];
    const float piz = pc[(b * 64 + i) * 3 + 2];
    dX[p] = pc[(b * 64 + p) * 3 + 0] - pix;
    dY[p] = pc[(b * 64 + p) * 3 + 1] - piy;
    dZ[p] = pc[(b * 64 + p) * 3 + 2] - piz;
  }
  __syncthreads();

  const float dlx = dX[lane], dly = dY[lane], dlz = dZ[lane];
  const float wl  = __builtin_amdgcn_exp2f(m2[lane]); // exp2(A_il[l]) per-lane
  const float aij = m0[lane];                          // lane also plays j here
  float* sTw = sT + wu * 128;
  float acc = 0.f;
  const v2f one2 = {1.f, 1.f};

  for (int kk0 = 2 * wu; kk0 < 64; kk0 += 8) {
    const int kk = __builtin_amdgcn_readfirstlane(kk0);
    v2f cx2[2], cy2[2], cz2[2], mm2[2];
#pragma unroll
    for (int t = 0; t < 2; ++t) {
      const int k = kk + t;
      const float dkx = dX[k], dky = dY[k], dkz = dZ[k];  // broadcast
      const float cx = dky * dlz - dkz * dly;             // d_k x d_l (per-lane)
      const float cy = dkz * dlx - dkx * dlz;
      const float cz = dkx * dly - dky * dlx;
      cx2[t] = (v2f){cx, cx};
      cy2[t] = (v2f){cy, cy};
      cz2[t] = (v2f){cz, cz};
      const float mv = m5[k * 64 + lane] * wl;            // R_kl * w_il
      mm2[t] = (v2f){mv, mv};
      // T row for this k (lane plays j): exp2(a_ij + a_jk + a_ik)
      const float Tv = __builtin_amdgcn_exp2f(aij + m3[k * 64 + lane] + m1[k]);
      sTw[t * 64 + lane] = Tv;
    }
    // same-wave LDS write->read: compiler inserts lgkmcnt wait; no barrier.
#pragma unroll 2
    for (int jp = 0; jp < 32; ++jp) {
      // dj from LDS: broadcast b128 {x0,x1,y0,y1} + b64 {z0,z1}
      const float4 Axy = *(const float4*)&sD[jp * 8];
      const v2f    zz  = *(const v2f*)&sD[jp * 8 + 4];
      v2f xx; xx.x = Axy.x; xx.y = Axy.y;      // subreg alias of the b128
      v2f yy; yy.x = Axy.z; yy.y = Axy.w;
      const v2f E01 = *(const v2f*)&sE[jp * 128 + lane * 2]; // per-lane b64
      v2f Tt[2];
      Tt[0] = *(const v2f*)&sTw[2 * jp];        // broadcast b64
      Tt[1] = *(const v2f*)&sTw[64 + 2 * jp];
#pragma unroll
      for (int t = 0; t < 2; ++t) {
        v2f e01, x01, p0, p1, det, d2;
        PKMUL(e01, E01, mm2[t]);                // E*mm
        PKFMA(x01, Tt[t], e01, one2);           // 1 + T*E*mm
        PKMUL(p0, zz, cz2[t]);                  // det = d_j . (d_k x d_l)
        PKFMA(p1, yy, cy2[t], p0);
        PKFMA(det, xx, cx2[t], p1);
        PKMUL(d2, det, det);
        float den = x01.x * x01.y;              // paired-rcp combine (scalar)
        float rd  = __builtin_amdgcn_rcpf(den);
        float num = fmaf(d2.x, x01.y, d2.y * x01.x);
        acc = fmaf(num, rd, acc);
      }
    }
  }

  // reduce: lanes sum over l; waves sum over their k slices
  for (int s = 32; s; s >>= 1) acc += __shfl_xor(acc, s, 64);
  if (lane == 0) wsum[wu] = acc;
  __syncthreads();
  if (tid == 0) {
    float blocksum = wsum[0] + wsum[1] + wsum[2] + wsum[3];
    atomicAdd(&pooled[b], blocksum * (1.f / 16777216.f)); // / N^4
  }
}

// ---------------------------------------------------------------------------
// Final tiny MLP: out[b] = gelu_tanh(pooled[b]*W1 + b1) @ W2 + b2
// ---------------------------------------------------------------------------
__global__ void simplex_final(
    const float* __restrict__ pooled,
    const float* __restrict__ W1, const float* __restrict__ b1,
    const float* __restrict__ W2, const float* __restrict__ b2,
    float* __restrict__ out)
{
  int t = threadIdx.x;
  if (t < BB) {
    float x = pooled[t];
    float o = b2[0];
    for (int c = 0; c < 32; ++c) {
      float z  = fmaf(x, W1[c], b1[c]);
      float z3 = z * z * z;
      float y  = 0.7978845608028654f * fmaf(0.044715f, z3, z);
      float ay = fabsf(y);
      float e  = __builtin_amdgcn_exp2f(2.8853900817779268f * ay);
      float th = 1.f - 2.f / (e + 1.f);
      th = copysignf(th, y);
      float gl = 0.5f * z * (1.f + th);
      o = fmaf(gl, W2[c], o);
    }
    out[t] = o;
  }
}

// ---------------------------------------------------------------------------
extern "C" void kernel_launch(void* const* d_in, const int* in_sizes, int n_in,
                              void* d_out, int out_size, void* d_ws, size_t ws_size,
                              hipStream_t stream) {
  (void)in_sizes; (void)n_in; (void)out_size; (void)ws_size;
  const float* pc  = (const float*)d_in[0];
  const float* Wq  = (const float*)d_in[1];
  const float* bq  = (const float*)d_in[2];
  const float* Wk1 = (const float*)d_in[3];
  const float* bk1 = (const float*)d_in[4];
  const float* Wk2 = (const float*)d_in[5];
  const float* bk2 = (const float*)d_in[6];
  const float* Wk3 = (const float*)d_in[7];
  const float* bk3 = (const float*)d_in[8];
  const float* W1  = (const float*)d_in[9];
  const float* b1  = (const float*)d_in[10];
  const float* W2  = (const float*)d_in[11];
  const float* b2  = (const float*)d_in[12];

  float* ws     = (float*)d_ws;
  float* pooled = ws + POOLED_OFF;
  float* out    = (float*)d_out;

  hipLaunchKernelGGL(simplex_phase1, dim3(BB * 7), dim3(256), 0, stream,
                     pc, Wq, bq, Wk1, bk1, Wk2, bk2, Wk3, bk3, ws);
  hipLaunchKernelGGL(simplex_main, dim3(BB * NN), dim3(256), 0, stream,
                     pc, ws, pooled);
  hipLaunchKernelGGL(simplex_final, dim3(1), dim3(64), 0, stream,
                     pooled, W1, b1, W2, b2, out);
}